// Round 13
// baseline (476.035 us; speedup 1.0000x reference)
//
#include <hip/hip_runtime.h>

typedef unsigned short ushort_t;
typedef __attribute__((ext_vector_type(8))) short bh8;
typedef __attribute__((ext_vector_type(4))) float f32x4;
typedef __attribute__((ext_vector_type(2))) unsigned int u32x2;
typedef __attribute__((ext_vector_type(4))) unsigned int u32x4;

#define DIM 256
#define DI 512
#define LEN 2048
#define BATCH 16
#define NROW (BATCH * LEN)   // 32768
#define NCHUNK (NROW / 8)

__device__ __forceinline__ float b2f(ushort_t u) {
    union { unsigned int i; float f; } v; v.i = ((unsigned int)u) << 16; return v.f;
}
__device__ __forceinline__ ushort_t f2b(float f) {
    union { float ff; unsigned int i; } v; v.ff = f;
    unsigned int x = v.i;
    x += 0x7fffu + ((x >> 16) & 1u);
    return (ushort_t)(x >> 16);
}
__device__ __forceinline__ float fexp2(float x) { float r; asm("v_exp_f32 %0, %1" : "=v"(r) : "v"(x)); return r; }
__device__ __forceinline__ float flog2(float x) { float r; asm("v_log_f32 %0, %1" : "=v"(r) : "v"(x)); return r; }
__device__ __forceinline__ float frcp (float x) { float r; asm("v_rcp_f32 %0, %1" : "=v"(r) : "v"(x)); return r; }
__device__ __forceinline__ unsigned int cvtpk(float lo, float hi) {
    unsigned int r; asm("v_cvt_pk_bf16_f32 %0, %1, %2" : "=v"(r) : "v"(lo), "v"(hi)); return r;
}
__device__ __forceinline__ float silu(float x) {
    return x * frcp(1.0f + fexp2(-1.44269504f * x));
}
// 8-lane butterfly sum within aligned 8-lane groups; all 8 lanes end with the sum
__device__ __forceinline__ float bsum8(float v) {
    float t;
    asm("v_add_f32_dpp %0, %1, %1 quad_perm:[1,0,3,2] row_mask:0xf bank_mask:0xf" : "=v"(t) : "v"(v));
    asm("v_add_f32_dpp %0, %1, %1 quad_perm:[2,3,0,1] row_mask:0xf bank_mask:0xf" : "=v"(v) : "v"(t));
    asm("v_add_f32_dpp %0, %1, %1 row_half_mirror row_mask:0xf bank_mask:0xf" : "=v"(t) : "v"(v));
    return t;
}
__device__ __forceinline__ void gload16(const void* g, void* l) {
    __builtin_amdgcn_global_load_lds((const __attribute__((address_space(1))) unsigned int*)g,
                                     (__attribute__((address_space(3))) unsigned int*)l, 16, 0, 0);
}

// ---------------- LayerNorm + channel swap: 1 row/wave, f32x4 loads ----------------
__global__ __launch_bounds__(256) void ln_swap_kernel(
    const float* __restrict__ x1, const float* __restrict__ x2,
    const float* __restrict__ ratio,
    const float* __restrict__ ln1w, const float* __restrict__ ln1b,
    const float* __restrict__ ln2w, const float* __restrict__ ln2b,
    ushort_t* __restrict__ xs1, ushort_t* __restrict__ xs2) {
    const int w = threadIdx.x >> 6, lane = threadIdx.x & 63;
    const int m = blockIdx.x * 4 + w;
    const int c0 = lane * 4;
    const size_t off = (size_t)m * DIM + c0;
    const f32x4 v1 = *(const f32x4*)(x1 + off);
    const f32x4 v2 = *(const f32x4*)(x2 + off);
    float s1 = 0.f, q1 = 0.f, s2 = 0.f, q2 = 0.f;
    #pragma unroll
    for (int k = 0; k < 4; k++) {
        s1 += v1[k]; q1 += v1[k] * v1[k];
        s2 += v2[k]; q2 += v2[k] * v2[k];
    }
    #pragma unroll
    for (int o = 32; o; o >>= 1) {
        s1 += __shfl_xor(s1, o); q1 += __shfl_xor(q1, o);
        s2 += __shfl_xor(s2, o); q2 += __shfl_xor(q2, o);
    }
    const float inv = 1.0f / DIM;
    const float mu1 = s1 * inv, mu2 = s2 * inv;
    const float r1 = rsqrtf(q1 * inv - mu1 * mu1 + 1e-5f);
    const float r2 = rsqrtf(q2 * inv - mu2 * mu2 + 1e-5f);
    const int nc = (int)(DIM / (1.0f + expf(-ratio[0])));   // = 159
    const f32x4 w1 = *(const f32x4*)(ln1w + c0), b1 = *(const f32x4*)(ln1b + c0);
    const f32x4 w2 = *(const f32x4*)(ln2w + c0), b2 = *(const f32x4*)(ln2b + c0);
    float n1[4], n2[4], o1v[4];
    #pragma unroll
    for (int k = 0; k < 4; k++) {
        n1[k] = (v1[k] - mu1) * r1 * w1[k] + b1[k];
        n2[k] = (v2[k] - mu2) * r2 * w2[k] + b2[k];
        o1v[k] = (c0 + k < nc) ? n2[k] : n1[k];
    }
    u32x2 p2, p1;
    p2[0] = cvtpk(n2[0], n2[1]);  p2[1] = cvtpk(n2[2], n2[3]);
    p1[0] = cvtpk(o1v[0], o1v[1]); p1[1] = cvtpk(o1v[2], o1v[3]);
    *(u32x2*)(&xs2[off]) = p2;
    *(u32x2*)(&xs1[off]) = p1;
}

// ---------------- convert weights fp32 -> bf16 (once per call) ----------------
#define WB_IN 0
#define WB_XP 262144
#define WB_OUT 286720
#define WB_TOT 417792
__global__ __launch_bounds__(256) void cvtw_kernel(
    const float* __restrict__ iw0, const float* __restrict__ iw1,
    const float* __restrict__ xw0, const float* __restrict__ xw1,
    const float* __restrict__ ow0, const float* __restrict__ ow1,
    ushort_t* __restrict__ o0, ushort_t* __restrict__ o1) {
    const int e = blockIdx.z;
    const float* iw = e ? iw1 : iw0;
    const float* xw = e ? xw1 : xw0;
    const float* ow = e ? ow1 : ow0;
    ushort_t* o = e ? o1 : o0;
    const int idx = blockIdx.x * 256 + threadIdx.x;
    if (idx < WB_XP) o[idx] = f2b(iw[idx]);
    else if (idx < WB_OUT) o[idx] = f2b(xw[idx - WB_XP]);
    else if (idx < WB_TOT) o[idx] = f2b(ow[idx - WB_OUT]);
}

// ---------------- in-proj GEMM: [u|z] = xs @ in_w^T ; outputs TRANSPOSED ----------------
__global__ __launch_bounds__(256) void gemm_in_kernel(
    const ushort_t* __restrict__ A0, const ushort_t* __restrict__ A1,
    const ushort_t* __restrict__ Wb0, const ushort_t* __restrict__ Wb1,
    ushort_t* __restrict__ uT0, ushort_t* __restrict__ uT1,
    ushort_t* __restrict__ zT0, ushort_t* __restrict__ zT1) {
    const int e = blockIdx.z;
    const ushort_t* __restrict__ A = e ? A1 : A0;
    const ushort_t* __restrict__ W = e ? Wb1 : Wb0;
    ushort_t* __restrict__ uT = e ? uT1 : uT0;
    ushort_t* __restrict__ zT = e ? zT1 : zT0;
    const int m0 = blockIdx.x * 128;
    const int n0 = blockIdx.y * 128;
    const int tid = threadIdx.x, lane = tid & 63, wv = tid >> 6;
    const int wr = wv >> 1, wc = wv & 1;

    __shared__ ushort_t sA[128 * 32];
    __shared__ ushort_t sW[128 * 32];

    f32x4 acc[4][4];
    #pragma unroll
    for (int i = 0; i < 4; i++)
        #pragma unroll
        for (int j = 0; j < 4; j++) acc[i][j] = (f32x4){0.f, 0.f, 0.f, 0.f};

    const ushort_t* Ap = A + (size_t)(m0 + wv * 32 + (lane >> 2)) * 256 + (lane & 3) * 8;
    const ushort_t* Wp = W + (size_t)(n0 + wv * 32 + (lane >> 2)) * 256 + (lane & 3) * 8;

    for (int kt = 0; kt < 256; kt += 32) {
        __syncthreads();
        gload16(Ap + kt,             &sA[(wv * 32) * 32]);
        gload16(Ap + kt + 16 * 256,  &sA[(wv * 32 + 16) * 32]);
        gload16(Wp + kt,             &sW[(wv * 32) * 32]);
        gload16(Wp + kt + 16 * 256,  &sW[(wv * 32 + 16) * 32]);
        __syncthreads();
        bh8 af[4], wf[4];
        #pragma unroll
        for (int i = 0; i < 4; i++)
            af[i] = *(const bh8*)(&sA[(wr * 64 + i * 16 + (lane & 15)) * 32 + (lane >> 4) * 8]);
        #pragma unroll
        for (int j = 0; j < 4; j++)
            wf[j] = *(const bh8*)(&sW[(wc * 64 + j * 16 + (lane & 15)) * 32 + (lane >> 4) * 8]);
        #pragma unroll
        for (int i = 0; i < 4; i++)
            #pragma unroll
            for (int j = 0; j < 4; j++)
                acc[i][j] = __builtin_amdgcn_mfma_f32_16x16x32_bf16(af[i], wf[j], acc[i][j], 0, 0, 0);
    }

    #pragma unroll
    for (int i = 0; i < 4; i++) {
        #pragma unroll
        for (int j = 0; j < 4; j++) {
            const int rbase = m0 + wr * 64 + i * 16 + (lane >> 4) * 4;
            const int col = n0 + wc * 64 + j * 16 + (lane & 15);
            u32x2 vv;
            vv[0] = cvtpk(acc[i][j][0], acc[i][j][1]);
            vv[1] = cvtpk(acc[i][j][2], acc[i][j][3]);
            if (col < DI) *(u32x2*)(&uT[(size_t)col * NROW + rbase]) = vv;
            else          *(u32x2*)(&zT[(size_t)(col - DI) * NROW + rbase]) = vv;
        }
    }
}

// ---------------- causal depthwise conv4 + SiLU, time-major ----------------
__global__ __launch_bounds__(256) void conv_silu_kernel(
    const ushort_t* __restrict__ uT0, const ushort_t* __restrict__ uT1,
    const float* __restrict__ cw0, const float* __restrict__ cw1,
    const float* __restrict__ cb0, const float* __restrict__ cb1,
    ushort_t* __restrict__ ucT0, ushort_t* __restrict__ ucT1) {
    const int e = blockIdx.z;
    const ushort_t* __restrict__ uT = e ? uT1 : uT0;
    const float* __restrict__ cw = e ? cw1 : cw0;
    const float* __restrict__ cb = e ? cb1 : cb0;
    ushort_t* __restrict__ ucT = e ? ucT1 : ucT0;

    const int g = blockIdx.x * 256 + threadIdx.x;
    const int c = g & (NCHUNK - 1);
    const int d = g >> 12;
    const int b = c >> 8;
    const int t0 = (c & 255) * 8;
    const size_t base = (size_t)d * NROW + b * LEN + t0;

    bh8 cur = *(const bh8*)(uT + base);
    float win[11];
    if (t0) {
        win[0] = b2f(uT[base - 3]); win[1] = b2f(uT[base - 2]); win[2] = b2f(uT[base - 1]);
    } else {
        win[0] = 0.f; win[1] = 0.f; win[2] = 0.f;
    }
    #pragma unroll
    for (int j = 0; j < 8; j++) win[3 + j] = b2f((ushort_t)cur[j]);
    const f32x4 w = *(const f32x4*)(cw + d * 4);
    const float bias = cb[d];
    float s[8];
    #pragma unroll
    for (int j = 0; j < 8; j++) {
        const float a = bias + w[0] * win[j] + w[1] * win[j + 1] + w[2] * win[j + 2] + w[3] * win[j + 3];
        s[j] = silu(a);
    }
    u32x4 o;
    #pragma unroll
    for (int k = 0; k < 4; k++) o[k] = cvtpk(s[2 * k], s[2 * k + 1]);
    *(u32x4*)(ucT + base) = o;
}

// ---------------- x-proj GEMM: rows 0..15 -> dblT[n][m]; rows 16..47 -> BCt packed ----------------
// BCt[m][32] layout: pos = sl*4 + {0:B_sl, 1:B_{sl+8}, 2:C_sl, 3:C_{sl+8}}  (sl in [0,8))
// so the scan reads one f32x4 per (t, sl).
__global__ __launch_bounds__(256) void gemm_xp_kernel(
    const ushort_t* __restrict__ ucT0, const ushort_t* __restrict__ ucT1,
    const ushort_t* __restrict__ Wb0, const ushort_t* __restrict__ Wb1,
    float* __restrict__ dbl0, float* __restrict__ dbl1,
    float* __restrict__ BCt0, float* __restrict__ BCt1) {
    const int e = blockIdx.z;
    const ushort_t* __restrict__ ucT = e ? ucT1 : ucT0;
    const ushort_t* __restrict__ W = (e ? Wb1 : Wb0) + WB_XP;
    float* __restrict__ dbl = e ? dbl1 : dbl0;
    float* __restrict__ BCt = e ? BCt1 : BCt0;
    const int m0 = blockIdx.x * 128;
    const int tid = threadIdx.x, lane = tid & 63;
    const int wc = tid >> 6;

    __shared__ ushort_t sW[48 * 40];
    __shared__ ushort_t sB[128 * 40];

    f32x4 acc[3][2];
    #pragma unroll
    for (int i = 0; i < 3; i++)
        #pragma unroll
        for (int j = 0; j < 2; j++) acc[i][j] = (f32x4){0.f, 0.f, 0.f, 0.f};

    const int kk = tid >> 3, mc = (tid & 7) * 16;
    const ushort_t* Bp = ucT + (size_t)kk * NROW + m0 + mc;

    for (int kt = 0; kt < 512; kt += 32) {
        __syncthreads();
        if (tid < 192) {
            const int r = tid >> 2, cc = (tid & 3) * 8;
            bh8 v = *(const bh8*)(W + (size_t)r * 512 + kt + cc);
            *(bh8*)(&sW[r * 40 + cc]) = v;
        }
        bh8 a0 = *(const bh8*)(Bp + (size_t)kt * NROW);
        bh8 a1 = *(const bh8*)(Bp + (size_t)kt * NROW + 8);
        #pragma unroll
        for (int q = 0; q < 8; q++) {
            sB[(mc + q) * 40 + kk] = (ushort_t)a0[q];
            sB[(mc + 8 + q) * 40 + kk] = (ushort_t)a1[q];
        }
        __syncthreads();
        bh8 af[3], wf[2];
        #pragma unroll
        for (int i = 0; i < 3; i++)
            af[i] = *(const bh8*)(&sW[(i * 16 + (lane & 15)) * 40 + (lane >> 4) * 8]);
        #pragma unroll
        for (int j = 0; j < 2; j++)
            wf[j] = *(const bh8*)(&sB[(wc * 32 + j * 16 + (lane & 15)) * 40 + (lane >> 4) * 8]);
        #pragma unroll
        for (int i = 0; i < 3; i++)
            #pragma unroll
            for (int j = 0; j < 2; j++)
                acc[i][j] = __builtin_amdgcn_mfma_f32_16x16x32_bf16(af[i], wf[j], acc[i][j], 0, 0, 0);
    }

    #pragma unroll
    for (int j = 0; j < 2; j++) {
        const int mm = m0 + wc * 32 + j * 16 + (lane & 15);
        {   // rows 0..15 -> dblT (delta-kernel input layout)
            const int nb = (lane >> 4) * 4;
            #pragma unroll
            for (int r = 0; r < 4; r++)
                dbl[(size_t)(nb + r) * NROW + mm] = acc[0][j][r];
        }
        #pragma unroll
        for (int i = 1; i < 3; i++) {   // rows 16..47 -> packed BCt positions
            #pragma unroll
            for (int r = 0; r < 4; r++) {
                const int sigma = (lane >> 4) * 4 + r;          // state index [0,16)
                const int pos = ((sigma & 7) << 2) + (sigma >> 3) + ((i == 2) ? 2 : 0);
                BCt[(size_t)mm * 32 + pos] = acc[i][j][r];
            }
        }
    }
}

// ---------------- delta = softplus(dt @ dt_w^T + dt_b), transposed I/O ----------------
__global__ __launch_bounds__(256) void delta_kernel(
    const float* __restrict__ dblT0, const float* __restrict__ dblT1,
    const float* __restrict__ dtw0, const float* __restrict__ dtw1,
    const float* __restrict__ dtb0, const float* __restrict__ dtb1,
    ushort_t* __restrict__ delT0, ushort_t* __restrict__ delT1) {
    const int e = blockIdx.z;
    const float* __restrict__ dblT = e ? dblT1 : dblT0;
    const float* __restrict__ dtw = e ? dtw1 : dtw0;
    const float* __restrict__ dtb = e ? dtb1 : dtb0;
    ushort_t* __restrict__ delT = e ? delT1 : delT0;

    const int tid = threadIdx.x, lane = tid & 63, wv = tid >> 6;
    const int bx = blockIdx.x;
    const int d = (bx & 127) * 4 + wv;
    const int m0 = (bx >> 7) * 256 + lane * 4;

    const float bias = dtb[d];
    f32x4 acc = {bias, bias, bias, bias};
    #pragma unroll
    for (int k = 0; k < 16; k++) {
        const float wk = dtw[d * 16 + k];
        const f32x4 bv = *(const f32x4*)(dblT + (size_t)k * NROW + m0);
        #pragma unroll
        for (int c = 0; c < 4; c++) acc[c] = fmaf(wk, bv[c], acc[c]);
    }
    float sp[4];
    #pragma unroll
    for (int c = 0; c < 4; c++) {
        const float x = acc[c];
        sp[c] = (x > 20.0f) ? x : 0.69314718f * flog2(1.0f + fexp2(1.44269504f * x));
    }
    u32x2 r;
    r[0] = cvtpk(sp[0], sp[1]);
    r[1] = cvtpk(sp[2], sp[3]);
    *(u32x2*)(&delT[(size_t)d * NROW + m0]) = r;
}

// ---------------- selective scan: 2 s-states/lane, swizzled d/u, packed-BC b128 reads ----------------
// yT aliases delT arena (write of chunk c happens after stage of chunk c+1 issued).
__global__ __launch_bounds__(256) void scan_kernel(
    const ushort_t* delT0, const ushort_t* delT1,               // alias yT: no restrict
    const ushort_t* __restrict__ ucT0, const ushort_t* __restrict__ ucT1,
    const float* __restrict__ BCt0, const float* __restrict__ BCt1,
    const float* __restrict__ al0, const float* __restrict__ al1,
    const float* __restrict__ Dp0, const float* __restrict__ Dp1,
    ushort_t* y0, ushort_t* y1) {
    // 512 blocks. XCD-aware: each XCD owns 4 (e,b) combos exclusively (16 dtiles each).
    const int gid = blockIdx.x;            // [0,512)
    const int xcd = gid & 7;
    const int k = gid >> 3;                // [0,64)
    const int combo = xcd * 4 + (k >> 4);  // [0,32)
    const int dtile = k & 15;              // [0,16): 32 d per tile
    const int e = combo & 1;
    const int b = combo >> 1;

    const ushort_t* delT = e ? delT1 : delT0;
    const ushort_t* __restrict__ ucT = e ? ucT1 : ucT0;
    const float* __restrict__ BCt = e ? BCt1 : BCt0;
    const float* __restrict__ al = e ? al1 : al0;
    const float* __restrict__ Dq = e ? Dp1 : Dp0;
    ushort_t* yo = e ? y1 : y0;

    const int tid = threadIdx.x;
    const int w = tid >> 6, lane = tid & 63;
    const int sl = lane & 7;               // s-lane: owns states sl and sl+8
    const int dloc = tid >> 3;             // [0,32): 8 lanes per d
    const int d = dtile * 32 + dloc;

    // double-buffered chunk stage (64 timesteps):
    //   sD/sU: [32 d][64 t] bf16, slot-swizzled (slot ^= row&7); sBC: [64 t][32] f32 packed
    __shared__ ushort_t sD[2][32 * 64];
    __shared__ ushort_t sU[2][32 * 64];
    __shared__ float sBC[2][64 * 32];

    // staging: thread covers row srow = tid>>3, 16B slot (tid&7); source col pre-swizzled
    // (rule 21: linear LDS dest + inverse-swizzled global source; read applies same XOR).
    const int srow = tid >> 3;
    const int scw = ((tid & 7) ^ (srow & 7)) * 8;
    const ushort_t* srcD = delT + (size_t)(dtile * 32 + srow) * NROW + b * LEN + scw;
    const ushort_t* srcU = ucT  + (size_t)(dtile * 32 + srow) * NROW + b * LEN + scw;
    const float* srcBC = BCt + (size_t)b * LEN * 32;

    const float A2a = -expf(al[(d << 4) + sl]) * 1.44269504f;
    const float A2b = -expf(al[(d << 4) + sl + 8]) * 1.44269504f;
    const float Dpv8 = Dq[d] * 0.125f;     // exact pow2 pre-scale: 8 lanes sum to u*Dp

    ushort_t* yp = yo + (size_t)d * NROW + b * LEN;

    // prologue: stage chunk 0
    gload16(srcD, &sD[0][srow * 64 + (tid & 7) * 8]);
    gload16(srcU, &sU[0][srow * 64 + (tid & 7) * 8]);
    gload16(srcBC + (w * 2 + 0) * 256 + lane * 4, &sBC[0][(w * 2 + 0) * 256]);
    gload16(srcBC + (w * 2 + 1) * 256 + lane * 4, &sBC[0][(w * 2 + 1) * 256]);
    __syncthreads();

    float h0 = 0.f, h1 = 0.f;
    for (int sup = 0; sup < 32; sup++) {
        const int q = sup & 1;
        {   // stage chunk sup+1 into the other buffer (last iter reads arena slack; safe)
            gload16(srcD + (sup + 1) * 64, &sD[q ^ 1][srow * 64 + (tid & 7) * 8]);
            gload16(srcU + (sup + 1) * 64, &sU[q ^ 1][srow * 64 + (tid & 7) * 8]);
            const float* sb = srcBC + (size_t)(sup + 1) * 2048;
            gload16(sb + (w * 2 + 0) * 256 + lane * 4, &sBC[q ^ 1][(w * 2 + 0) * 256]);
            gload16(sb + (w * 2 + 1) * 256 + lane * 4, &sBC[q ^ 1][(w * 2 + 1) * 256]);
        }
        #pragma unroll
        for (int sub = 0; sub < 8; sub++) {
            const int sw = ((sub ^ (dloc & 7)) << 3);            // un-swizzle slot
            const bh8 dv = *(const bh8*)(&sD[q][dloc * 64 + sw]);
            const bh8 uv = *(const bh8*)(&sU[q][dloc * 64 + sw]);
            float yv[8];
            #pragma unroll
            for (int j = 0; j < 8; j++) {
                const int t = sub * 8 + j;
                const float dt = b2f((ushort_t)dv[j]);
                const float uf = b2f((ushort_t)uv[j]);
                const float dtuf = dt * uf;
                const f32x4 bc = *(const f32x4*)(&sBC[q][t * 32 + sl * 4]);  // {B0,B1,C0,C1}
                h0 = fmaf(h0, fexp2(dt * A2a), dtuf * bc[0]);
                h1 = fmaf(h1, fexp2(dt * A2b), dtuf * bc[1]);
                yv[j] = fmaf(uf, Dpv8, fmaf(h1, bc[3], h0 * bc[2]));
            }
            #pragma unroll
            for (int j = 0; j < 8; j++) yv[j] = bsum8(yv[j]);    // sum over 8 sl-lanes
            u32x4 o;
            #pragma unroll
            for (int kk = 0; kk < 4; kk++)
                o[kk] = cvtpk(yv[2 * kk], yv[2 * kk + 1]);
            if (sl == 0) *(u32x4*)(yp + sup * 64 + sub * 8) = o;
        }
        __syncthreads();   // buffer q consumed by all; stage of q^1 drained (vmcnt before barrier)
    }
}

// ---------------- out-proj GEMM with FUSED GATE: o = (y*silu(z)) @ out_w^T + residual ----------------
__global__ __launch_bounds__(256) void gemm_out_kernel(
    const ushort_t* __restrict__ yT0, const ushort_t* __restrict__ yT1,
    const ushort_t* __restrict__ zT0, const ushort_t* __restrict__ zT1,
    const ushort_t* __restrict__ Wb0, const ushort_t* __restrict__ Wb1,
    const float* __restrict__ r0, const float* __restrict__ r1,
    float* __restrict__ o0, float* __restrict__ o1) {
    const int e = blockIdx.z;
    const ushort_t* __restrict__ yT = e ? yT1 : yT0;
    const ushort_t* __restrict__ zT = e ? zT1 : zT0;
    const ushort_t* __restrict__ W = (e ? Wb1 : Wb0) + WB_OUT;
    const float* __restrict__ rr = e ? r1 : r0;
    float* __restrict__ oo = e ? o1 : o0;
    const int m0 = blockIdx.x * 128;
    const int n0 = blockIdx.y * 128;
    const int tid = threadIdx.x, lane = tid & 63, wv = tid >> 6;
    const int wr = wv >> 1, wc = wv & 1;

    __shared__ ushort_t sA[128 * 40];
    __shared__ ushort_t sW[128 * 32];

    f32x4 acc[4][4];
    #pragma unroll
    for (int i = 0; i < 4; i++)
        #pragma unroll
        for (int j = 0; j < 4; j++) acc[i][j] = (f32x4){0.f, 0.f, 0.f, 0.f};

    const int kk = tid >> 3, mc = (tid & 7) * 16;
    const ushort_t* Yp = yT + (size_t)kk * NROW + m0 + mc;
    const ushort_t* Zp = zT + (size_t)kk * NROW + m0 + mc;
    const ushort_t* Wp = W + (size_t)(n0 + wv * 32 + (lane >> 2)) * 512 + (lane & 3) * 8;

    for (int kt = 0; kt < 512; kt += 32) {
        __syncthreads();
        gload16(Wp + kt,             &sW[(wv * 32) * 32]);
        gload16(Wp + kt + 16 * 512,  &sW[(wv * 32 + 16) * 32]);
        bh8 a0 = *(const bh8*)(Yp + (size_t)kt * NROW);
        bh8 a1 = *(const bh8*)(Yp + (size_t)kt * NROW + 8);
        bh8 z0 = *(const bh8*)(Zp + (size_t)kt * NROW);
        bh8 z1 = *(const bh8*)(Zp + (size_t)kt * NROW + 8);
        #pragma unroll
        for (int q = 0; q < 4; q++) {
            const unsigned int p0 = cvtpk(
                b2f((ushort_t)a0[2 * q])     * silu(b2f((ushort_t)z0[2 * q])),
                b2f((ushort_t)a0[2 * q + 1]) * silu(b2f((ushort_t)z0[2 * q + 1])));
            const unsigned int p1 = cvtpk(
                b2f((ushort_t)a1[2 * q])     * silu(b2f((ushort_t)z1[2 * q])),
                b2f((ushort_t)a1[2 * q + 1]) * silu(b2f((ushort_t)z1[2 * q + 1])));
            sA[(mc + 2 * q) * 40 + kk]     = (ushort_t)p0;
            sA[(mc + 2 * q + 1) * 40 + kk] = (ushort_t)(p0 >> 16);
            sA[(mc + 8 + 2 * q) * 40 + kk]     = (ushort_t)p1;
            sA[(mc + 8 + 2 * q + 1) * 40 + kk] = (ushort_t)(p1 >> 16);
        }
        __syncthreads();
        bh8 af[4], wf[4];
        #pragma unroll
        for (int i = 0; i < 4; i++)
            af[i] = *(const bh8*)(&sA[(wr * 64 + i * 16 + (lane & 15)) * 40 + (lane >> 4) * 8]);
        #pragma unroll
        for (int j = 0; j < 4; j++)
            wf[j] = *(const bh8*)(&sW[(wc * 64 + j * 16 + (lane & 15)) * 32 + (lane >> 4) * 8]);
        #pragma unroll
        for (int i = 0; i < 4; i++)
            #pragma unroll
            for (int j = 0; j < 4; j++)
                acc[i][j] = __builtin_amdgcn_mfma_f32_16x16x32_bf16(af[i], wf[j], acc[i][j], 0, 0, 0);
    }

    #pragma unroll
    for (int i = 0; i < 4; i++) {
        #pragma unroll
        for (int j = 0; j < 4; j++) {
            const int rbase = m0 + wr * 64 + i * 16 + (lane >> 4) * 4;
            const int col = n0 + wc * 64 + j * 16 + (lane & 15);
            #pragma unroll
            for (int r = 0; r < 4; r++) {
                const size_t off = (size_t)(rbase + r) * DIM + col;
                oo[off] = acc[i][j][r] + rr[off];
            }
        }
    }
}

extern "C" void kernel_launch(void* const* d_in, const int* in_sizes, int n_in,
                              void* d_out, int out_size, void* d_ws, size_t ws_size,
                              hipStream_t stream) {
    const float* x1    = (const float*)d_in[0];
    const float* x2    = (const float*)d_in[1];
    const float* ratio = (const float*)d_in[2];
    const float* ln1w  = (const float*)d_in[3];
    const float* ln1b  = (const float*)d_in[4];
    const float* ln2w  = (const float*)d_in[5];
    const float* ln2b  = (const float*)d_in[6];
    const float* inw[2]   = {(const float*)d_in[7],  (const float*)d_in[16]};
    const float* convw[2] = {(const float*)d_in[8],  (const float*)d_in[17]};
    const float* convb[2] = {(const float*)d_in[9],  (const float*)d_in[18]};
    const float* xprw[2]  = {(const float*)d_in[10], (const float*)d_in[19]};
    const float* dtw[2]   = {(const float*)d_in[11], (const float*)d_in[20]};
    const float* dtb[2]   = {(const float*)d_in[12], (const float*)d_in[21]};
    const float* alog[2]  = {(const float*)d_in[13], (const float*)d_in[22]};
    const float* Dp[2]    = {(const float*)d_in[14], (const float*)d_in[23]};
    const float* outw[2]  = {(const float*)d_in[15], (const float*)d_in[24]};

    // d_out map (fp32 o1 | o2, 33.55 MB each):
    //   xs[e]  bf16 @ bytes [0, 16.78M)
    //   dbl[e] f32  @ [16.78M, 18.87M)   (16 rows x NROW)
    //   BCt[e] f32  @ [18.87M, 23.07M)   ([NROW][32] packed B|C)
    // All dead before out-proj writes o1/o2. Scan BC prefetch may read up to 8KB
    // past BCt end (still inside the d_out half).
    float* o1 = (float*)d_out;
    float* o2 = o1 + (size_t)NROW * DIM;
    ushort_t* xs[2] = {(ushort_t*)o1, (ushort_t*)o2};
    const size_t XS_BYTES  = (size_t)NROW * DIM * 2;
    const size_t DBL_BYTES = (size_t)16 * NROW * 4;
    float* dbl[2] = {(float*)((char*)o1 + XS_BYTES), (float*)((char*)o2 + XS_BYTES)};
    float* BCt[2] = {(float*)((char*)o1 + XS_BYTES + DBL_BYTES),
                     (float*)((char*)o2 + XS_BYTES + DBL_BYTES)};

    // ws arenas (~203 MB): uT[2] (-> delT -> yT), zT[2], ucT[2], wbf[2]
    const size_t SZ_DI = (size_t)NROW * DI * 2;
    const size_t SZ_WB = ((size_t)WB_TOT * 2 + 255) & ~(size_t)255;
    char* p = (char*)d_ws;
    ushort_t* uT[2]  = {(ushort_t*)p, (ushort_t*)(p + SZ_DI)};            p += 2 * SZ_DI;
    ushort_t* zT[2]  = {(ushort_t*)p, (ushort_t*)(p + SZ_DI)};            p += 2 * SZ_DI;
    ushort_t* ucT[2] = {(ushort_t*)p, (ushort_t*)(p + SZ_DI)};            p += 2 * SZ_DI;
    ushort_t* wbf[2] = {(ushort_t*)p, (ushort_t*)(p + SZ_WB)};
    ushort_t* delT[2] = {uT[0], uT[1]};   // uT dead after conv
    ushort_t* yT[2]   = {uT[0], uT[1]};   // scan writes yT over delT

    ln_swap_kernel<<<NROW / 4, 256, 0, stream>>>(x1, x2, ratio, ln1w, ln1b, ln2w, ln2b, xs[0], xs[1]);

    cvtw_kernel<<<dim3(WB_TOT / 256, 1, 2), 256, 0, stream>>>(
        inw[0], inw[1], xprw[0], xprw[1], outw[0], outw[1], wbf[0], wbf[1]);

    gemm_in_kernel<<<dim3(NROW / 128, 8, 2), 256, 0, stream>>>(
        xs[0], xs[1], wbf[0], wbf[1], uT[0], uT[1], zT[0], zT[1]);

    conv_silu_kernel<<<dim3((DI * NCHUNK) / 256, 1, 2), 256, 0, stream>>>(
        uT[0], uT[1], convw[0], convw[1], convb[0], convb[1], ucT[0], ucT[1]);

    gemm_xp_kernel<<<dim3(NROW / 128, 1, 2), 256, 0, stream>>>(
        ucT[0], ucT[1], wbf[0], wbf[1], dbl[0], dbl[1], BCt[0], BCt[1]);

    delta_kernel<<<dim3(128 * 128, 1, 2), 256, 0, stream>>>(
        dbl[0], dbl[1], dtw[0], dtw[1], dtb[0], dtb[1], delT[0], delT[1]);

    scan_kernel<<<dim3(512), 256, 0, stream>>>(
        delT[0], delT[1], ucT[0], ucT[1], BCt[0], BCt[1],
        alog[0], alog[1], Dp[0], Dp[1], yT[0], yT[1]);

    gemm_out_kernel<<<dim3(NROW / 128, 2, 2), 256, 0, stream>>>(
        yT[0], yT[1], zT[0], zT[1], wbf[0], wbf[1], x1, x2, o1, o2);
}

// Round 14
// 451.236 us; speedup vs baseline: 1.0550x; 1.0550x over previous
//
#include <hip/hip_runtime.h>

typedef unsigned short ushort_t;
typedef __attribute__((ext_vector_type(8))) short bh8;
typedef __attribute__((ext_vector_type(4))) float f32x4;
typedef __attribute__((ext_vector_type(2))) unsigned int u32x2;
typedef __attribute__((ext_vector_type(4))) unsigned int u32x4;

#define DIM 256
#define DI 512
#define LEN 2048
#define BATCH 16
#define NROW (BATCH * LEN)   // 32768
#define NCHUNK (NROW / 8)

__device__ __forceinline__ float b2f(ushort_t u) {
    union { unsigned int i; float f; } v; v.i = ((unsigned int)u) << 16; return v.f;
}
__device__ __forceinline__ ushort_t f2b(float f) {
    union { float ff; unsigned int i; } v; v.ff = f;
    unsigned int x = v.i;
    x += 0x7fffu + ((x >> 16) & 1u);
    return (ushort_t)(x >> 16);
}
__device__ __forceinline__ float fexp2(float x) { float r; asm("v_exp_f32 %0, %1" : "=v"(r) : "v"(x)); return r; }
__device__ __forceinline__ float flog2(float x) { float r; asm("v_log_f32 %0, %1" : "=v"(r) : "v"(x)); return r; }
__device__ __forceinline__ float frcp (float x) { float r; asm("v_rcp_f32 %0, %1" : "=v"(r) : "v"(x)); return r; }
__device__ __forceinline__ unsigned int cvtpk(float lo, float hi) {
    unsigned int r; asm("v_cvt_pk_bf16_f32 %0, %1, %2" : "=v"(r) : "v"(lo), "v"(hi)); return r;
}
__device__ __forceinline__ float silu(float x) {
    return x * frcp(1.0f + fexp2(-1.44269504f * x));
}
// 8-lane butterfly sum within aligned 8-lane groups; all 8 lanes end with the sum
__device__ __forceinline__ float bsum8(float v) {
    float t;
    asm("v_add_f32_dpp %0, %1, %1 quad_perm:[1,0,3,2] row_mask:0xf bank_mask:0xf" : "=v"(t) : "v"(v));
    asm("v_add_f32_dpp %0, %1, %1 quad_perm:[2,3,0,1] row_mask:0xf bank_mask:0xf" : "=v"(v) : "v"(t));
    asm("v_add_f32_dpp %0, %1, %1 row_half_mirror row_mask:0xf bank_mask:0xf" : "=v"(t) : "v"(v));
    return t;
}
__device__ __forceinline__ void gload16(const void* g, void* l) {
    __builtin_amdgcn_global_load_lds((const __attribute__((address_space(1))) unsigned int*)g,
                                     (__attribute__((address_space(3))) unsigned int*)l, 16, 0, 0);
}

// ---------------- LayerNorm + channel swap: 1 row/wave, f32x4 loads ----------------
__global__ __launch_bounds__(256) void ln_swap_kernel(
    const float* __restrict__ x1, const float* __restrict__ x2,
    const float* __restrict__ ratio,
    const float* __restrict__ ln1w, const float* __restrict__ ln1b,
    const float* __restrict__ ln2w, const float* __restrict__ ln2b,
    ushort_t* __restrict__ xs1, ushort_t* __restrict__ xs2) {
    const int w = threadIdx.x >> 6, lane = threadIdx.x & 63;
    const int m = blockIdx.x * 4 + w;
    const int c0 = lane * 4;
    const size_t off = (size_t)m * DIM + c0;
    const f32x4 v1 = *(const f32x4*)(x1 + off);
    const f32x4 v2 = *(const f32x4*)(x2 + off);
    float s1 = 0.f, q1 = 0.f, s2 = 0.f, q2 = 0.f;
    #pragma unroll
    for (int k = 0; k < 4; k++) {
        s1 += v1[k]; q1 += v1[k] * v1[k];
        s2 += v2[k]; q2 += v2[k] * v2[k];
    }
    #pragma unroll
    for (int o = 32; o; o >>= 1) {
        s1 += __shfl_xor(s1, o); q1 += __shfl_xor(q1, o);
        s2 += __shfl_xor(s2, o); q2 += __shfl_xor(q2, o);
    }
    const float inv = 1.0f / DIM;
    const float mu1 = s1 * inv, mu2 = s2 * inv;
    const float r1 = rsqrtf(q1 * inv - mu1 * mu1 + 1e-5f);
    const float r2 = rsqrtf(q2 * inv - mu2 * mu2 + 1e-5f);
    const int nc = (int)(DIM / (1.0f + expf(-ratio[0])));   // = 159
    const f32x4 w1 = *(const f32x4*)(ln1w + c0), b1 = *(const f32x4*)(ln1b + c0);
    const f32x4 w2 = *(const f32x4*)(ln2w + c0), b2 = *(const f32x4*)(ln2b + c0);
    float n1[4], n2[4], o1v[4];
    #pragma unroll
    for (int k = 0; k < 4; k++) {
        n1[k] = (v1[k] - mu1) * r1 * w1[k] + b1[k];
        n2[k] = (v2[k] - mu2) * r2 * w2[k] + b2[k];
        o1v[k] = (c0 + k < nc) ? n2[k] : n1[k];
    }
    u32x2 p2, p1;
    p2[0] = cvtpk(n2[0], n2[1]);  p2[1] = cvtpk(n2[2], n2[3]);
    p1[0] = cvtpk(o1v[0], o1v[1]); p1[1] = cvtpk(o1v[2], o1v[3]);
    *(u32x2*)(&xs2[off]) = p2;
    *(u32x2*)(&xs1[off]) = p1;
}

// ---------------- convert weights fp32 -> bf16 (once per call) ----------------
#define WB_IN 0
#define WB_XP 262144
#define WB_OUT 286720
#define WB_TOT 417792
__global__ __launch_bounds__(256) void cvtw_kernel(
    const float* __restrict__ iw0, const float* __restrict__ iw1,
    const float* __restrict__ xw0, const float* __restrict__ xw1,
    const float* __restrict__ ow0, const float* __restrict__ ow1,
    ushort_t* __restrict__ o0, ushort_t* __restrict__ o1) {
    const int e = blockIdx.z;
    const float* iw = e ? iw1 : iw0;
    const float* xw = e ? xw1 : xw0;
    const float* ow = e ? ow1 : ow0;
    ushort_t* o = e ? o1 : o0;
    const int idx = blockIdx.x * 256 + threadIdx.x;
    if (idx < WB_XP) o[idx] = f2b(iw[idx]);
    else if (idx < WB_OUT) o[idx] = f2b(xw[idx - WB_XP]);
    else if (idx < WB_TOT) o[idx] = f2b(ow[idx - WB_OUT]);
}

// ---------------- in-proj GEMM: [u|z] = xs @ in_w^T ; XCD-chunked dispatch ----------------
// flat grid 2048: xcd = g&7 owns 32 consecutive m-tiles x all 8 n-tiles so the
// A-panel (2 MB) + W (0.5 MB) stay L2-resident per XCD (8x A-reuse in L2).
__global__ __launch_bounds__(256) void gemm_in_kernel(
    const ushort_t* __restrict__ A0, const ushort_t* __restrict__ A1,
    const ushort_t* __restrict__ Wb0, const ushort_t* __restrict__ Wb1,
    ushort_t* __restrict__ uT0, ushort_t* __restrict__ uT1,
    ushort_t* __restrict__ zT0, ushort_t* __restrict__ zT1) {
    const int e = blockIdx.z;
    const ushort_t* __restrict__ A = e ? A1 : A0;
    const ushort_t* __restrict__ W = e ? Wb1 : Wb0;
    ushort_t* __restrict__ uT = e ? uT1 : uT0;
    ushort_t* __restrict__ zT = e ? zT1 : zT0;
    const int g = blockIdx.x;               // [0, 2048)
    const int xcd = g & 7;
    const int idx = g >> 3;                 // [0, 256)
    const int n0 = (idx & 7) * 128;
    const int m0 = (xcd * 32 + (idx >> 3)) * 128;
    const int tid = threadIdx.x, lane = tid & 63, wv = tid >> 6;
    const int wr = wv >> 1, wc = wv & 1;

    __shared__ ushort_t sA[128 * 32];
    __shared__ ushort_t sW[128 * 32];

    f32x4 acc[4][4];
    #pragma unroll
    for (int i = 0; i < 4; i++)
        #pragma unroll
        for (int j = 0; j < 4; j++) acc[i][j] = (f32x4){0.f, 0.f, 0.f, 0.f};

    const ushort_t* Ap = A + (size_t)(m0 + wv * 32 + (lane >> 2)) * 256 + (lane & 3) * 8;
    const ushort_t* Wp = W + (size_t)(n0 + wv * 32 + (lane >> 2)) * 256 + (lane & 3) * 8;

    for (int kt = 0; kt < 256; kt += 32) {
        __syncthreads();
        gload16(Ap + kt,             &sA[(wv * 32) * 32]);
        gload16(Ap + kt + 16 * 256,  &sA[(wv * 32 + 16) * 32]);
        gload16(Wp + kt,             &sW[(wv * 32) * 32]);
        gload16(Wp + kt + 16 * 256,  &sW[(wv * 32 + 16) * 32]);
        __syncthreads();
        bh8 af[4], wf[4];
        #pragma unroll
        for (int i = 0; i < 4; i++)
            af[i] = *(const bh8*)(&sA[(wr * 64 + i * 16 + (lane & 15)) * 32 + (lane >> 4) * 8]);
        #pragma unroll
        for (int j = 0; j < 4; j++)
            wf[j] = *(const bh8*)(&sW[(wc * 64 + j * 16 + (lane & 15)) * 32 + (lane >> 4) * 8]);
        #pragma unroll
        for (int i = 0; i < 4; i++)
            #pragma unroll
            for (int j = 0; j < 4; j++)
                acc[i][j] = __builtin_amdgcn_mfma_f32_16x16x32_bf16(af[i], wf[j], acc[i][j], 0, 0, 0);
    }

    #pragma unroll
    for (int i = 0; i < 4; i++) {
        #pragma unroll
        for (int j = 0; j < 4; j++) {
            const int rbase = m0 + wr * 64 + i * 16 + (lane >> 4) * 4;
            const int col = n0 + wc * 64 + j * 16 + (lane & 15);
            u32x2 vv;
            vv[0] = cvtpk(acc[i][j][0], acc[i][j][1]);
            vv[1] = cvtpk(acc[i][j][2], acc[i][j][3]);
            if (col < DI) *(u32x2*)(&uT[(size_t)col * NROW + rbase]) = vv;
            else          *(u32x2*)(&zT[(size_t)(col - DI) * NROW + rbase]) = vv;
        }
    }
}

// ---------------- causal depthwise conv4 + SiLU, time-major ----------------
__global__ __launch_bounds__(256) void conv_silu_kernel(
    const ushort_t* __restrict__ uT0, const ushort_t* __restrict__ uT1,
    const float* __restrict__ cw0, const float* __restrict__ cw1,
    const float* __restrict__ cb0, const float* __restrict__ cb1,
    ushort_t* __restrict__ ucT0, ushort_t* __restrict__ ucT1) {
    const int e = blockIdx.z;
    const ushort_t* __restrict__ uT = e ? uT1 : uT0;
    const float* __restrict__ cw = e ? cw1 : cw0;
    const float* __restrict__ cb = e ? cb1 : cb0;
    ushort_t* __restrict__ ucT = e ? ucT1 : ucT0;

    const int g = blockIdx.x * 256 + threadIdx.x;
    const int c = g & (NCHUNK - 1);
    const int d = g >> 12;
    const int b = c >> 8;
    const int t0 = (c & 255) * 8;
    const size_t base = (size_t)d * NROW + b * LEN + t0;

    bh8 cur = *(const bh8*)(uT + base);
    float win[11];
    if (t0) {
        win[0] = b2f(uT[base - 3]); win[1] = b2f(uT[base - 2]); win[2] = b2f(uT[base - 1]);
    } else {
        win[0] = 0.f; win[1] = 0.f; win[2] = 0.f;
    }
    #pragma unroll
    for (int j = 0; j < 8; j++) win[3 + j] = b2f((ushort_t)cur[j]);
    const f32x4 w = *(const f32x4*)(cw + d * 4);
    const float bias = cb[d];
    float s[8];
    #pragma unroll
    for (int j = 0; j < 8; j++) {
        const float a = bias + w[0] * win[j] + w[1] * win[j + 1] + w[2] * win[j + 2] + w[3] * win[j + 3];
        s[j] = silu(a);
    }
    u32x4 o;
    #pragma unroll
    for (int k = 0; k < 4; k++) o[k] = cvtpk(s[2 * k], s[2 * k + 1]);
    *(u32x4*)(ucT + base) = o;
}

// ---------------- x-proj GEMM: rows 0..15 -> dblT[n][m]; rows 16..47 -> BCt packed ----------------
// BCt[m][32] layout: pos = sl*4 + {0:B_sl, 1:B_{sl+8}, 2:C_sl, 3:C_{sl+8}}  (sl in [0,8))
__global__ __launch_bounds__(256) void gemm_xp_kernel(
    const ushort_t* __restrict__ ucT0, const ushort_t* __restrict__ ucT1,
    const ushort_t* __restrict__ Wb0, const ushort_t* __restrict__ Wb1,
    float* __restrict__ dbl0, float* __restrict__ dbl1,
    float* __restrict__ BCt0, float* __restrict__ BCt1) {
    const int e = blockIdx.z;
    const ushort_t* __restrict__ ucT = e ? ucT1 : ucT0;
    const ushort_t* __restrict__ W = (e ? Wb1 : Wb0) + WB_XP;
    float* __restrict__ dbl = e ? dbl1 : dbl0;
    float* __restrict__ BCt = e ? BCt1 : BCt0;
    const int m0 = blockIdx.x * 128;
    const int tid = threadIdx.x, lane = tid & 63;
    const int wc = tid >> 6;

    __shared__ ushort_t sW[48 * 40];
    __shared__ ushort_t sB[128 * 40];

    f32x4 acc[3][2];
    #pragma unroll
    for (int i = 0; i < 3; i++)
        #pragma unroll
        for (int j = 0; j < 2; j++) acc[i][j] = (f32x4){0.f, 0.f, 0.f, 0.f};

    const int kk = tid >> 3, mc = (tid & 7) * 16;
    const ushort_t* Bp = ucT + (size_t)kk * NROW + m0 + mc;

    for (int kt = 0; kt < 512; kt += 32) {
        __syncthreads();
        if (tid < 192) {
            const int r = tid >> 2, cc = (tid & 3) * 8;
            bh8 v = *(const bh8*)(W + (size_t)r * 512 + kt + cc);
            *(bh8*)(&sW[r * 40 + cc]) = v;
        }
        bh8 a0 = *(const bh8*)(Bp + (size_t)kt * NROW);
        bh8 a1 = *(const bh8*)(Bp + (size_t)kt * NROW + 8);
        #pragma unroll
        for (int q = 0; q < 8; q++) {
            sB[(mc + q) * 40 + kk] = (ushort_t)a0[q];
            sB[(mc + 8 + q) * 40 + kk] = (ushort_t)a1[q];
        }
        __syncthreads();
        bh8 af[3], wf[2];
        #pragma unroll
        for (int i = 0; i < 3; i++)
            af[i] = *(const bh8*)(&sW[(i * 16 + (lane & 15)) * 40 + (lane >> 4) * 8]);
        #pragma unroll
        for (int j = 0; j < 2; j++)
            wf[j] = *(const bh8*)(&sB[(wc * 32 + j * 16 + (lane & 15)) * 40 + (lane >> 4) * 8]);
        #pragma unroll
        for (int i = 0; i < 3; i++)
            #pragma unroll
            for (int j = 0; j < 2; j++)
                acc[i][j] = __builtin_amdgcn_mfma_f32_16x16x32_bf16(af[i], wf[j], acc[i][j], 0, 0, 0);
    }

    #pragma unroll
    for (int j = 0; j < 2; j++) {
        const int mm = m0 + wc * 32 + j * 16 + (lane & 15);
        {   // rows 0..15 -> dblT (delta-kernel input layout)
            const int nb = (lane >> 4) * 4;
            #pragma unroll
            for (int r = 0; r < 4; r++)
                dbl[(size_t)(nb + r) * NROW + mm] = acc[0][j][r];
        }
        #pragma unroll
        for (int i = 1; i < 3; i++) {   // rows 16..47 -> packed BCt positions
            #pragma unroll
            for (int r = 0; r < 4; r++) {
                const int sigma = (lane >> 4) * 4 + r;          // state index [0,16)
                const int pos = ((sigma & 7) << 2) + (sigma >> 3) + ((i == 2) ? 2 : 0);
                BCt[(size_t)mm * 32 + pos] = acc[i][j][r];
            }
        }
    }
}

// ---------------- delta = softplus(dt @ dt_w^T + dt_b), transposed I/O ----------------
__global__ __launch_bounds__(256) void delta_kernel(
    const float* __restrict__ dblT0, const float* __restrict__ dblT1,
    const float* __restrict__ dtw0, const float* __restrict__ dtw1,
    const float* __restrict__ dtb0, const float* __restrict__ dtb1,
    ushort_t* __restrict__ delT0, ushort_t* __restrict__ delT1) {
    const int e = blockIdx.z;
    const float* __restrict__ dblT = e ? dblT1 : dblT0;
    const float* __restrict__ dtw = e ? dtw1 : dtw0;
    const float* __restrict__ dtb = e ? dtb1 : dtb0;
    ushort_t* __restrict__ delT = e ? delT1 : delT0;

    const int tid = threadIdx.x, lane = tid & 63, wv = tid >> 6;
    const int bx = blockIdx.x;
    const int d = (bx & 127) * 4 + wv;
    const int m0 = (bx >> 7) * 256 + lane * 4;

    const float bias = dtb[d];
    f32x4 acc = {bias, bias, bias, bias};
    #pragma unroll
    for (int k = 0; k < 16; k++) {
        const float wk = dtw[d * 16 + k];
        const f32x4 bv = *(const f32x4*)(dblT + (size_t)k * NROW + m0);
        #pragma unroll
        for (int c = 0; c < 4; c++) acc[c] = fmaf(wk, bv[c], acc[c]);
    }
    float sp[4];
    #pragma unroll
    for (int c = 0; c < 4; c++) {
        const float x = acc[c];
        sp[c] = (x > 20.0f) ? x : 0.69314718f * flog2(1.0f + fexp2(1.44269504f * x));
    }
    u32x2 r;
    r[0] = cvtpk(sp[0], sp[1]);
    r[1] = cvtpk(sp[2], sp[3]);
    *(u32x2*)(&delT[(size_t)d * NROW + m0]) = r;
}

// ---------------- selective scan: 2 s-states/lane, swizzled d/u, packed-BC b128 reads ----------------
// yT aliases delT arena (write of chunk c happens after stage of chunk c+1 issued).
__global__ __launch_bounds__(256) void scan_kernel(
    const ushort_t* delT0, const ushort_t* delT1,               // alias yT: no restrict
    const ushort_t* __restrict__ ucT0, const ushort_t* __restrict__ ucT1,
    const float* __restrict__ BCt0, const float* __restrict__ BCt1,
    const float* __restrict__ al0, const float* __restrict__ al1,
    const float* __restrict__ Dp0, const float* __restrict__ Dp1,
    ushort_t* y0, ushort_t* y1) {
    // 512 blocks. XCD-aware: each XCD owns 4 (e,b) combos exclusively (16 dtiles each).
    const int gid = blockIdx.x;            // [0,512)
    const int xcd = gid & 7;
    const int k = gid >> 3;                // [0,64)
    const int combo = xcd * 4 + (k >> 4);  // [0,32)
    const int dtile = k & 15;              // [0,16): 32 d per tile
    const int e = combo & 1;
    const int b = combo >> 1;

    const ushort_t* delT = e ? delT1 : delT0;
    const ushort_t* __restrict__ ucT = e ? ucT1 : ucT0;
    const float* __restrict__ BCt = e ? BCt1 : BCt0;
    const float* __restrict__ al = e ? al1 : al0;
    const float* __restrict__ Dq = e ? Dp1 : Dp0;
    ushort_t* yo = e ? y1 : y0;

    const int tid = threadIdx.x;
    const int w = tid >> 6, lane = tid & 63;
    const int sl = lane & 7;               // s-lane: owns states sl and sl+8
    const int dloc = tid >> 3;             // [0,32): 8 lanes per d
    const int d = dtile * 32 + dloc;

    __shared__ ushort_t sD[2][32 * 64];
    __shared__ ushort_t sU[2][32 * 64];
    __shared__ float sBC[2][64 * 32];

    const int srow = tid >> 3;
    const int scw = ((tid & 7) ^ (srow & 7)) * 8;
    const ushort_t* srcD = delT + (size_t)(dtile * 32 + srow) * NROW + b * LEN + scw;
    const ushort_t* srcU = ucT  + (size_t)(dtile * 32 + srow) * NROW + b * LEN + scw;
    const float* srcBC = BCt + (size_t)b * LEN * 32;

    const float A2a = -expf(al[(d << 4) + sl]) * 1.44269504f;
    const float A2b = -expf(al[(d << 4) + sl + 8]) * 1.44269504f;
    const float Dpv8 = Dq[d] * 0.125f;     // exact pow2 pre-scale: 8 lanes sum to u*Dp

    ushort_t* yp = yo + (size_t)d * NROW + b * LEN;

    gload16(srcD, &sD[0][srow * 64 + (tid & 7) * 8]);
    gload16(srcU, &sU[0][srow * 64 + (tid & 7) * 8]);
    gload16(srcBC + (w * 2 + 0) * 256 + lane * 4, &sBC[0][(w * 2 + 0) * 256]);
    gload16(srcBC + (w * 2 + 1) * 256 + lane * 4, &sBC[0][(w * 2 + 1) * 256]);
    __syncthreads();

    float h0 = 0.f, h1 = 0.f;
    for (int sup = 0; sup < 32; sup++) {
        const int q = sup & 1;
        {   // stage chunk sup+1 into the other buffer (last iter reads arena slack; safe)
            gload16(srcD + (sup + 1) * 64, &sD[q ^ 1][srow * 64 + (tid & 7) * 8]);
            gload16(srcU + (sup + 1) * 64, &sU[q ^ 1][srow * 64 + (tid & 7) * 8]);
            const float* sb = srcBC + (size_t)(sup + 1) * 2048;
            gload16(sb + (w * 2 + 0) * 256 + lane * 4, &sBC[q ^ 1][(w * 2 + 0) * 256]);
            gload16(sb + (w * 2 + 1) * 256 + lane * 4, &sBC[q ^ 1][(w * 2 + 1) * 256]);
        }
        #pragma unroll
        for (int sub = 0; sub < 8; sub++) {
            const int sw = ((sub ^ (dloc & 7)) << 3);            // un-swizzle slot
            const bh8 dv = *(const bh8*)(&sD[q][dloc * 64 + sw]);
            const bh8 uv = *(const bh8*)(&sU[q][dloc * 64 + sw]);
            float yv[8];
            #pragma unroll
            for (int j = 0; j < 8; j++) {
                const int t = sub * 8 + j;
                const float dt = b2f((ushort_t)dv[j]);
                const float uf = b2f((ushort_t)uv[j]);
                const float dtuf = dt * uf;
                const f32x4 bc = *(const f32x4*)(&sBC[q][t * 32 + sl * 4]);  // {B0,B1,C0,C1}
                h0 = fmaf(h0, fexp2(dt * A2a), dtuf * bc[0]);
                h1 = fmaf(h1, fexp2(dt * A2b), dtuf * bc[1]);
                yv[j] = fmaf(uf, Dpv8, fmaf(h1, bc[3], h0 * bc[2]));
            }
            #pragma unroll
            for (int j = 0; j < 8; j++) yv[j] = bsum8(yv[j]);    // sum over 8 sl-lanes
            u32x4 o;
            #pragma unroll
            for (int kk = 0; kk < 4; kk++)
                o[kk] = cvtpk(yv[2 * kk], yv[2 * kk + 1]);
            if (sl == 0) *(u32x4*)(yp + sup * 64 + sub * 8) = o;
        }
        __syncthreads();   // buffer q consumed by all; stage of q^1 drained (vmcnt before barrier)
    }
}

// ---------------- out-proj GEMM, BN=256 single-pass, FUSED GATE ----------------
// 512 threads (8 waves, 2x4 wave grid, wave tile 64x64). Waves 0-3 stage gated A
// (y*silu(z) scatter into padded sA); waves 4-7 gload16 the 256x32 W tile.
// Eliminates the grid.y=2 duplicate y/z reads + duplicate gate compute.
__global__ __launch_bounds__(512) void gemm_out_kernel(
    const ushort_t* __restrict__ yT0, const ushort_t* __restrict__ yT1,
    const ushort_t* __restrict__ zT0, const ushort_t* __restrict__ zT1,
    const ushort_t* __restrict__ Wb0, const ushort_t* __restrict__ Wb1,
    const float* __restrict__ r0, const float* __restrict__ r1,
    float* __restrict__ o0, float* __restrict__ o1) {
    const int e = blockIdx.z;
    const ushort_t* __restrict__ yT = e ? yT1 : yT0;
    const ushort_t* __restrict__ zT = e ? zT1 : zT0;
    const ushort_t* __restrict__ W = (e ? Wb1 : Wb0) + WB_OUT;
    const float* __restrict__ rr = e ? r1 : r0;
    float* __restrict__ oo = e ? o1 : o0;
    const int m0 = blockIdx.x * 128;
    const int tid = threadIdx.x, lane = tid & 63, wv = tid >> 6;   // wv in [0,8)
    const int wr = wv & 1, wc = wv >> 1;                            // 2 x 4 wave grid

    __shared__ ushort_t sA[128 * 40];
    __shared__ ushort_t sW[256 * 32];

    f32x4 acc[4][4];
    #pragma unroll
    for (int i = 0; i < 4; i++)
        #pragma unroll
        for (int j = 0; j < 4; j++) acc[i][j] = (f32x4){0.f, 0.f, 0.f, 0.f};

    // A-staging addressing (threads 0..255)
    const int kk = tid >> 3, mc = (tid & 7) * 16;
    const ushort_t* Yp = yT + (size_t)kk * NROW + m0 + mc;
    const ushort_t* Zp = zT + (size_t)kk * NROW + m0 + mc;
    // W-staging addressing (waves 4..7: 64 rows each via 4 gload16)
    const int wq = (wv >= 4) ? (wv - 4) : 0;
    const ushort_t* Wp = W + (size_t)(wq * 64 + (lane >> 2)) * 512 + (lane & 3) * 8;

    for (int kt = 0; kt < 512; kt += 32) {
        __syncthreads();
        if (wv >= 4) {
            #pragma unroll
            for (int i = 0; i < 4; i++)
                gload16(Wp + kt + (size_t)i * 16 * 512, &sW[(wq * 64 + i * 16) * 32]);
        } else {
            bh8 a0 = *(const bh8*)(Yp + (size_t)kt * NROW);
            bh8 a1 = *(const bh8*)(Yp + (size_t)kt * NROW + 8);
            bh8 z0 = *(const bh8*)(Zp + (size_t)kt * NROW);
            bh8 z1 = *(const bh8*)(Zp + (size_t)kt * NROW + 8);
            #pragma unroll
            for (int q = 0; q < 4; q++) {
                const unsigned int p0 = cvtpk(
                    b2f((ushort_t)a0[2 * q])     * silu(b2f((ushort_t)z0[2 * q])),
                    b2f((ushort_t)a0[2 * q + 1]) * silu(b2f((ushort_t)z0[2 * q + 1])));
                const unsigned int p1 = cvtpk(
                    b2f((ushort_t)a1[2 * q])     * silu(b2f((ushort_t)z1[2 * q])),
                    b2f((ushort_t)a1[2 * q + 1]) * silu(b2f((ushort_t)z1[2 * q + 1])));
                sA[(mc + 2 * q) * 40 + kk]     = (ushort_t)p0;
                sA[(mc + 2 * q + 1) * 40 + kk] = (ushort_t)(p0 >> 16);
                sA[(mc + 8 + 2 * q) * 40 + kk]     = (ushort_t)p1;
                sA[(mc + 8 + 2 * q + 1) * 40 + kk] = (ushort_t)(p1 >> 16);
            }
        }
        __syncthreads();
        bh8 af[4], wf[4];
        #pragma unroll
        for (int i = 0; i < 4; i++)
            af[i] = *(const bh8*)(&sA[(wr * 64 + i * 16 + (lane & 15)) * 40 + (lane >> 4) * 8]);
        #pragma unroll
        for (int j = 0; j < 4; j++)
            wf[j] = *(const bh8*)(&sW[(wc * 64 + j * 16 + (lane & 15)) * 32 + (lane >> 4) * 8]);
        #pragma unroll
        for (int i = 0; i < 4; i++)
            #pragma unroll
            for (int j = 0; j < 4; j++)
                acc[i][j] = __builtin_amdgcn_mfma_f32_16x16x32_bf16(af[i], wf[j], acc[i][j], 0, 0, 0);
    }

    #pragma unroll
    for (int i = 0; i < 4; i++) {
        #pragma unroll
        for (int j = 0; j < 4; j++) {
            const int rbase = m0 + wr * 64 + i * 16 + (lane >> 4) * 4;
            const int col = wc * 64 + j * 16 + (lane & 15);
            #pragma unroll
            for (int r = 0; r < 4; r++) {
                const size_t off = (size_t)(rbase + r) * DIM + col;
                oo[off] = acc[i][j][r] + rr[off];
            }
        }
    }
}

extern "C" void kernel_launch(void* const* d_in, const int* in_sizes, int n_in,
                              void* d_out, int out_size, void* d_ws, size_t ws_size,
                              hipStream_t stream) {
    const float* x1    = (const float*)d_in[0];
    const float* x2    = (const float*)d_in[1];
    const float* ratio = (const float*)d_in[2];
    const float* ln1w  = (const float*)d_in[3];
    const float* ln1b  = (const float*)d_in[4];
    const float* ln2w  = (const float*)d_in[5];
    const float* ln2b  = (const float*)d_in[6];
    const float* inw[2]   = {(const float*)d_in[7],  (const float*)d_in[16]};
    const float* convw[2] = {(const float*)d_in[8],  (const float*)d_in[17]};
    const float* convb[2] = {(const float*)d_in[9],  (const float*)d_in[18]};
    const float* xprw[2]  = {(const float*)d_in[10], (const float*)d_in[19]};
    const float* dtw[2]   = {(const float*)d_in[11], (const float*)d_in[20]};
    const float* dtb[2]   = {(const float*)d_in[12], (const float*)d_in[21]};
    const float* alog[2]  = {(const float*)d_in[13], (const float*)d_in[22]};
    const float* Dp[2]    = {(const float*)d_in[14], (const float*)d_in[23]};
    const float* outw[2]  = {(const float*)d_in[15], (const float*)d_in[24]};

    // d_out map (fp32 o1 | o2, 33.55 MB each):
    //   xs[e]  bf16 @ bytes [0, 16.78M)
    //   dbl[e] f32  @ [16.78M, 18.87M)   (16 rows x NROW)
    //   BCt[e] f32  @ [18.87M, 23.07M)   ([NROW][32] packed B|C)
    // All dead before out-proj writes o1/o2. Scan BC prefetch may read up to 8KB
    // past BCt end (still inside the d_out half).
    float* o1 = (float*)d_out;
    float* o2 = o1 + (size_t)NROW * DIM;
    ushort_t* xs[2] = {(ushort_t*)o1, (ushort_t*)o2};
    const size_t XS_BYTES  = (size_t)NROW * DIM * 2;
    const size_t DBL_BYTES = (size_t)16 * NROW * 4;
    float* dbl[2] = {(float*)((char*)o1 + XS_BYTES), (float*)((char*)o2 + XS_BYTES)};
    float* BCt[2] = {(float*)((char*)o1 + XS_BYTES + DBL_BYTES),
                     (float*)((char*)o2 + XS_BYTES + DBL_BYTES)};

    // ws arenas (~203 MB): uT[2] (-> delT -> yT), zT[2], ucT[2], wbf[2]
    const size_t SZ_DI = (size_t)NROW * DI * 2;
    const size_t SZ_WB = ((size_t)WB_TOT * 2 + 255) & ~(size_t)255;
    char* p = (char*)d_ws;
    ushort_t* uT[2]  = {(ushort_t*)p, (ushort_t*)(p + SZ_DI)};            p += 2 * SZ_DI;
    ushort_t* zT[2]  = {(ushort_t*)p, (ushort_t*)(p + SZ_DI)};            p += 2 * SZ_DI;
    ushort_t* ucT[2] = {(ushort_t*)p, (ushort_t*)(p + SZ_DI)};            p += 2 * SZ_DI;
    ushort_t* wbf[2] = {(ushort_t*)p, (ushort_t*)(p + SZ_WB)};
    ushort_t* delT[2] = {uT[0], uT[1]};   // uT dead after conv
    ushort_t* yT[2]   = {uT[0], uT[1]};   // scan writes yT over delT

    ln_swap_kernel<<<NROW / 4, 256, 0, stream>>>(x1, x2, ratio, ln1w, ln1b, ln2w, ln2b, xs[0], xs[1]);

    cvtw_kernel<<<dim3(WB_TOT / 256, 1, 2), 256, 0, stream>>>(
        inw[0], inw[1], xprw[0], xprw[1], outw[0], outw[1], wbf[0], wbf[1]);

    gemm_in_kernel<<<dim3(2048, 1, 2), 256, 0, stream>>>(
        xs[0], xs[1], wbf[0], wbf[1], uT[0], uT[1], zT[0], zT[1]);

    conv_silu_kernel<<<dim3((DI * NCHUNK) / 256, 1, 2), 256, 0, stream>>>(
        uT[0], uT[1], convw[0], convw[1], convb[0], convb[1], ucT[0], ucT[1]);

    gemm_xp_kernel<<<dim3(NROW / 128, 1, 2), 256, 0, stream>>>(
        ucT[0], ucT[1], wbf[0], wbf[1], dbl[0], dbl[1], BCt[0], BCt[1]);

    delta_kernel<<<dim3(128 * 128, 1, 2), 256, 0, stream>>>(
        dbl[0], dbl[1], dtw[0], dtw[1], dtb[0], dtb[1], delT[0], delT[1]);

    scan_kernel<<<dim3(512), 256, 0, stream>>>(
        delT[0], delT[1], ucT[0], ucT[1], BCt[0], BCt[1],
        alog[0], alog[1], Dp[0], Dp[1], yT[0], yT[1]);

    gemm_out_kernel<<<dim3(NROW / 128, 1, 2), 512, 0, stream>>>(
        yT[0], yT[1], zT[0], zT[1], wbf[0], wbf[1], x1, x2, o1, o2);
}